// Round 5
// baseline (327.990 us; speedup 1.0000x reference)
//
#include <hip/hip_runtime.h>
#include <cstdint>
#include <cstddef>

#define B_   4
#define N_   1024
#define D_   2048
#define HQ_  16
#define HKV_ 4
#define DH_  128
#define E_   3072

#define SCALE_ 0.08838834764831845  // 128^-0.5

typedef __attribute__((ext_vector_type(8))) short frag16;
typedef __attribute__((ext_vector_type(4))) float fragf4;
#define MFMA16(a, b, c) __builtin_amdgcn_mfma_f32_16x16x32_bf16(a, b, c, 0, 0, 0)

__device__ __forceinline__ short f2bf(float f) {
  union { float f; uint32_t u; } a; a.f = f;
  uint32_t r = (a.u + 0x7fffu + ((a.u >> 16) & 1u)) >> 16;  // RNE
  return (short)r;
}
__device__ __forceinline__ short f2bf_t(float f) {  // truncate (p>=0)
  union { float f; uint32_t u; } a; a.f = f;
  return (short)(a.u >> 16);
}
__device__ __forceinline__ void async_copy16(const void* g, void* l) {
  __builtin_amdgcn_global_load_lds(
      (const __attribute__((address_space(1))) void*)g,
      (__attribute__((address_space(3))) void*)l, 16, 0, 0);
}

// ---------------------------------------------------------------------------
// fp32 -> bf16 conversion, 8 elems/thread
// ---------------------------------------------------------------------------
__global__ __launch_bounds__(256) void f2bf_kernel(const float* __restrict__ src,
                                                   short* __restrict__ dst, int n) {
  const int i = (blockIdx.x * 256 + threadIdx.x) * 8;
  if (i >= n) return;
  float4 a = *(const float4*)(src + i);
  float4 b = *(const float4*)(src + i + 4);
  union { frag16 f; short s[8]; } u;
  u.s[0] = f2bf(a.x); u.s[1] = f2bf(a.y); u.s[2] = f2bf(a.z); u.s[3] = f2bf(a.w);
  u.s[4] = f2bf(b.x); u.s[5] = f2bf(b.y); u.s[6] = f2bf(b.z); u.s[7] = f2bf(b.w);
  *(frag16*)(dst + i) = u.f;
}

// ---------------------------------------------------------------------------
// bf16 MFMA GEMM: C[M][Nc] = A[M][K] * W[Nc][K]^T.  M fixed = 4096 (32 tiles).
// 128x128 C-tile, 4 waves (2x2 of 64x64), BK=32, global_load_lds staging.
// LDS bank-conflict fix: logical k-chunk c of row r stored at physical chunk
// (c + (r>>1)) & 3  -> frag reads cover all 32 banks 2-way (free).
// Grid: 1D, XCD-panel mapping: xcd = bid&7 owns n-cols [xcd*ncpx, ...) so its
// W-panel (ncpx*128 rows of W) stays L2-resident.
// ---------------------------------------------------------------------------
template <typename OutT>
__global__ __launch_bounds__(256) void gemm_mfma(const short* __restrict__ A,
                                                 const short* __restrict__ Wt,
                                                 OutT* __restrict__ C,
                                                 int Nc, int K, int ncpx) {
  __shared__ __align__(16) short As[128][32];
  __shared__ __align__(16) short Bs[128][32];

  const int bid = blockIdx.x;
  const int xcd = bid & 7, j = bid >> 3;
  const int m0 = (j & 31) * 128;
  const int n0 = (xcd * ncpx + (j >> 5)) * 128;

  const int tid = threadIdx.x;
  const int lane = tid & 63;
  const int w = tid >> 6;
  const int ln = lane & 15, g = lane >> 4;
  const int wm = (w >> 1) * 64, wn = (w & 1) * 64;

  // staging: lane l -> row slab*16 + (l>>2), physical chunk l&3 holds
  // logical chunk ((l&3) - ((l>>3)&3)) & 3
  const int srow = lane >> 2;
  const int scol = (((lane & 3) - ((lane >> 3) & 3)) & 3) * 8;
  // frag-read swizzled chunk offset (loop-invariant)
  const int rcol = ((g + (ln >> 1)) & 3) * 8;

  fragf4 acc[4][4];
#pragma unroll
  for (int i = 0; i < 4; ++i)
#pragma unroll
    for (int jj = 0; jj < 4; ++jj) acc[i][jj] = (fragf4){0.f, 0.f, 0.f, 0.f};

  for (int k0 = 0; k0 < K; k0 += 32) {
    __syncthreads();
#pragma unroll
    for (int i = 0; i < 2; ++i) {
      const int slab = w * 2 + i;
      const int r = slab * 16 + srow;
      async_copy16(A  + (size_t)(m0 + r) * K + k0 + scol, &As[slab * 16][0]);
      async_copy16(Wt + (size_t)(n0 + r) * K + k0 + scol, &Bs[slab * 16][0]);
    }
    __syncthreads();

    frag16 af[4], bf[4];
#pragma unroll
    for (int t = 0; t < 4; ++t) {
      af[t] = *(const frag16*)&As[wm + t * 16 + ln][rcol];
      bf[t] = *(const frag16*)&Bs[wn + t * 16 + ln][rcol];
    }
#pragma unroll
    for (int i = 0; i < 4; ++i)
#pragma unroll
      for (int jj = 0; jj < 4; ++jj) acc[i][jj] = MFMA16(af[i], bf[jj], acc[i][jj]);
  }

#pragma unroll
  for (int i = 0; i < 4; ++i) {
#pragma unroll
    for (int jj = 0; jj < 4; ++jj) {
#pragma unroll
      for (int r = 0; r < 4; ++r) {
        const size_t idx = (size_t)(m0 + wm + i * 16 + 4 * g + r) * Nc +
                           (n0 + wn + jj * 16 + ln);
        if constexpr (sizeof(OutT) == 2) C[idx] = f2bf(acc[i][jj][r]);
        else                             C[idx] = acc[i][jj][r];
      }
    }
  }
}

// ---------------------------------------------------------------------------
// Fused RMSNorm + RoPE (unchanged)
// ---------------------------------------------------------------------------
__global__ __launch_bounds__(256) void normrope(short* __restrict__ qkvb,
                                                const int* __restrict__ pos,
                                                const float* __restrict__ qw,
                                                const float* __restrict__ kw) {
  const int gid = blockIdx.x * 256 + threadIdx.x;
  const int lane = gid & 63;
  const int wid = gid >> 6;
  const int hh = wid % (HQ_ + HKV_);
  const int n  = (wid / (HQ_ + HKV_)) % N_;
  const int b  = wid / ((HQ_ + HKV_) * N_);

  int eoff; const float* w;
  if (hh < HQ_) { eoff = hh * DH_;              w = qw; }
  else          { eoff = D_ + (hh - HQ_) * DH_; w = kw; }

  short* base = qkvb + ((size_t)b * N_ + n) * E_ + eoff;
  union { uint32_t u; float f; } c1, c2;
  c1.u = ((uint32_t)(uint16_t)base[lane]) << 16;
  c2.u = ((uint32_t)(uint16_t)base[64 + lane]) << 16;
  float t1 = c1.f, t2 = c2.f;

  float ss = t1 * t1 + t2 * t2;
#pragma unroll
  for (int off = 32; off; off >>= 1) ss += __shfl_xor(ss, off);
  const float r = rsqrtf(ss * (1.0f / 128.0f) + 1.1920928955078125e-07f);
  t1 = t1 * r * w[lane];
  t2 = t2 * r * w[64 + lane];

  const float invf = (float)exp2(-(double)lane * 0.20762050593046014);
  const float ang = (float)pos[n] * invf;
  const float c = cosf(ang), s = sinf(ang);
  base[lane]      = f2bf(t1 * c - t2 * s);
  base[64 + lane] = f2bf(t2 * c + t1 * s);
}

// ---------------------------------------------------------------------------
// V transpose (unchanged)
// ---------------------------------------------------------------------------
__global__ __launch_bounds__(256) void vtrans(const short* __restrict__ qkvb,
                                              short* __restrict__ vtg) {
  __shared__ short T[128 * 72];
  const int n0 = blockIdx.x * 64, kh = blockIdx.y, b = blockIdx.z;
  const int tid = threadIdx.x;
  {
    const int r = tid & 63, dc = (tid >> 6) * 32;
    const short* src = qkvb + ((size_t)b * N_ + n0 + r) * E_ + 2560 + kh * DH_ + dc;
    union { frag16 f; short s[8]; } u;
#pragma unroll
    for (int i = 0; i < 4; ++i) {
      u.f = *(const frag16*)(src + 8 * i);
#pragma unroll
      for (int jj = 0; jj < 8; ++jj) T[(dc + 8 * i + jj) * 72 + r] = u.s[jj];
    }
  }
  __syncthreads();
  {
    const int d = tid & 127, e = tid >> 7;
    short* dst = vtg + ((size_t)(b * HKV_ + kh) * DH_ + d) * N_ + n0 + e * 32;
#pragma unroll
    for (int i = 0; i < 4; ++i)
      *(frag16*)(dst + 8 * i) = *(const frag16*)&T[d * 72 + e * 32 + 8 * i];
  }
}

// ---------------------------------------------------------------------------
// bf16-MFMA flash attention, fixed-max softmax (unchanged from round 4)
// ---------------------------------------------------------------------------
__global__ __launch_bounds__(256) void attn_mfma(const short* __restrict__ qkvb,
                                                 const short* __restrict__ vtg,
                                                 short* __restrict__ yb) {
  const int bx = blockIdx.x;
  const int qt = 63 - (bx >> 4);
  const int id = bx & 15;
  const int kh = id & 3, b = id >> 2;
  const int q0 = qt * 16;

  __shared__ __align__(16) short lds_[22600];
  const int VT0 = 8704, PS0 = 17992;

  const int tid = threadIdx.x;
  const int lane = tid & 63;
  const int w = tid >> 6;
  const int ln = lane & 15, g = lane >> 4, g8 = g * 8;
  const int h = kh * 4 + w;

  const short* qb = qkvb + (size_t)b * N_ * E_ + h * DH_;
  const short* kb = qkvb + (size_t)b * N_ * E_ + D_ + kh * DH_;
  const short* vt = vtg + (size_t)(b * HKV_ + kh) * DH_ * N_;

  if (tid < 64) lds_[VT0 + 128 * 72 + tid] = (short)0x3F80;

  frag16 qf[4];
  {
    const short* qrow = qb + (size_t)(q0 + ln) * E_ + g8;
#pragma unroll
    for (int c = 0; c < 4; ++c) qf[c] = *(const frag16*)(qrow + c * 32);
  }

  fragf4 o[8], ol = (fragf4){0.f, 0.f, 0.f, 0.f};
#pragma unroll
  for (int dt = 0; dt < 8; ++dt) o[dt] = (fragf4){0.f, 0.f, 0.f, 0.f};

  const float SC2 = (float)(SCALE_ * 1.4426950408889634);
  const float MB2 = (float)(12.0 * 1.4426950408889634);

  const int ntiles = qt / 4 + 1;
  for (int kt = 0; kt < ntiles; ++kt) {
    const int kbase = kt * 64;
    __syncthreads();
    {
      const int r = tid & 63, c = (tid >> 6) * 32;
      const short* src = kb + (size_t)(kbase + r) * E_ + c;
#pragma unroll
      for (int i = 0; i < 4; ++i)
        *(frag16*)&lds_[r * 136 + c + 8 * i] = *(const frag16*)(src + 8 * i);
    }
    {
      const int d = tid & 127, e = tid >> 7;
      const short* src = vt + (size_t)d * N_ + kbase + e * 32;
#pragma unroll
      for (int i = 0; i < 4; ++i)
        *(frag16*)&lds_[VT0 + d * 72 + e * 32 + 8 * i] = *(const frag16*)(src + 8 * i);
    }
    __syncthreads();

    fragf4 s[4];
#pragma unroll
    for (int st = 0; st < 4; ++st) s[st] = (fragf4){0.f, 0.f, 0.f, 0.f};
#pragma unroll
    for (int c = 0; c < 4; ++c) {
      frag16 qc = qf[c];
#pragma unroll
      for (int st = 0; st < 4; ++st) {
        frag16 kf = *(const frag16*)&lds_[(st * 16 + ln) * 136 + c * 32 + g8];
        s[st] = MFMA16(qc, kf, s[st]);
      }
    }

    const bool full = (kbase + 63) <= q0;
#pragma unroll
    for (int st = 0; st < 4; ++st) {
      const int kg = kbase + st * 16 + ln;
#pragma unroll
      for (int r2 = 0; r2 < 4; ++r2) {
        float sv = s[st][r2];
        if (!full && kg > q0 + 4 * g + r2) sv = -1.0e30f;
        const float p = exp2f(fmaf(sv, SC2, -MB2));
        lds_[PS0 + (w * 16 + 4 * g + r2) * 72 + st * 16 + ln] = f2bf_t(p);
      }
    }

    frag16 pf0 = *(const frag16*)&lds_[PS0 + (w * 16 + ln) * 72 + g8];
    frag16 pf1 = *(const frag16*)&lds_[PS0 + (w * 16 + ln) * 72 + 32 + g8];
#pragma unroll
    for (int dt = 0; dt < 8; ++dt) {
      frag16 v0 = *(const frag16*)&lds_[VT0 + (dt * 16 + ln) * 72 + g8];
      frag16 v1 = *(const frag16*)&lds_[VT0 + (dt * 16 + ln) * 72 + 32 + g8];
      o[dt] = MFMA16(pf0, v0, o[dt]);
      o[dt] = MFMA16(pf1, v1, o[dt]);
    }
    {
      frag16 vl0 = *(const frag16*)&lds_[VT0 + (128 + ln) * 72 + g8];
      frag16 vl1 = *(const frag16*)&lds_[VT0 + (128 + ln) * 72 + 32 + g8];
      ol = MFMA16(pf0, vl0, ol);
      ol = MFMA16(pf1, vl1, ol);
    }
  }

#pragma unroll
  for (int r2 = 0; r2 < 4; ++r2) {
    const float lv = __shfl(ol[r2], lane & 48);
    const float inv = 1.0f / lv;
    short* yrow = yb + ((size_t)b * N_ + q0 + 4 * g + r2) * D_ + h * DH_;
#pragma unroll
    for (int dt = 0; dt < 8; ++dt) yrow[dt * 16 + ln] = f2bf(o[dt][r2] * inv);
  }
}

// ---------------------------------------------------------------------------
extern "C" void kernel_launch(void* const* d_in, const int* in_sizes, int n_in,
                              void* d_out, int out_size, void* d_ws, size_t ws_size,
                              hipStream_t stream) {
  const float* x     = (const float*)d_in[0];
  const int*   pos   = (const int*)d_in[2];
  const float* w_qkv = (const float*)d_in[3];
  const float* w_out = (const float*)d_in[4];
  const float* qw    = (const float*)d_in[5];
  const float* kw    = (const float*)d_in[6];
  float* out = (float*)d_out;

  short* qkvb = (short*)d_ws;
  short* yb   = qkvb + (size_t)B_ * N_ * E_;
  short* xb   = yb   + (size_t)B_ * N_ * D_;
  short* wqb  = xb   + (size_t)B_ * N_ * D_;
  short* wob  = wqb  + (size_t)E_ * D_;
  short* vtg  = xb;  // alias, used post-gemm1

  const int nx = B_ * N_ * D_, nwq = E_ * D_, nwo = D_ * D_;
  f2bf_kernel<<<nx  / 2048, 256, 0, stream>>>(x,     xb,  nx);
  f2bf_kernel<<<nwq / 2048, 256, 0, stream>>>(w_qkv, wqb, nwq);
  f2bf_kernel<<<nwo / 2048, 256, 0, stream>>>(w_out, wob, nwo);

  // GEMM1: M=4096, Nc=3072, K=2048 -> 768 blocks, ncpx = 3
  gemm_mfma<short><<<768, 256, 0, stream>>>(xb, wqb, qkvb, E_, D_, 3);

  normrope<<<(B_ * N_ * (HQ_ + HKV_) * 64) / 256, 256, 0, stream>>>(
      qkvb, pos, qw, kw);

  vtrans<<<dim3(N_ / 64, HKV_, B_), 256, 0, stream>>>(qkvb, vtg);

  attn_mfma<<<1024, 256, 0, stream>>>(qkvb, vtg, yb);

  // GEMM2: M=4096, Nc=2048, K=2048 -> 512 blocks, ncpx = 2
  gemm_mfma<float><<<512, 256, 0, stream>>>(yb, wob, out, D_, D_, 2);
}

// Round 6
// 304.059 us; speedup vs baseline: 1.0787x; 1.0787x over previous
//
#include <hip/hip_runtime.h>
#include <cstdint>
#include <cstddef>

#define B_   4
#define N_   1024
#define D_   2048
#define HQ_  16
#define HKV_ 4
#define DH_  128
#define E_   3072

#define SCALE_ 0.08838834764831845  // 128^-0.5

typedef __attribute__((ext_vector_type(8))) short frag16;
typedef __attribute__((ext_vector_type(4))) float fragf4;
#define MFMA16(a, b, c) __builtin_amdgcn_mfma_f32_16x16x32_bf16(a, b, c, 0, 0, 0)

__device__ __forceinline__ short f2bf(float f) {
  union { float f; uint32_t u; } a; a.f = f;
  uint32_t r = (a.u + 0x7fffu + ((a.u >> 16) & 1u)) >> 16;  // RNE
  return (short)r;
}
__device__ __forceinline__ short f2bf_t(float f) {  // truncate (p>=0)
  union { float f; uint32_t u; } a; a.f = f;
  return (short)(a.u >> 16);
}
__device__ __forceinline__ void async_copy16(const void* g, void* l) {
  __builtin_amdgcn_global_load_lds(
      (const __attribute__((address_space(1))) void*)g,
      (__attribute__((address_space(3))) void*)l, 16, 0, 0);
}

// ---------------------------------------------------------------------------
// fused fp32 -> bf16 conversion for all three tensors (one launch)
// ---------------------------------------------------------------------------
__global__ __launch_bounds__(256) void f2bf3_kernel(
    const float* __restrict__ s0, short* __restrict__ d0, int b0,
    const float* __restrict__ s1, short* __restrict__ d1, int b1,
    const float* __restrict__ s2, short* __restrict__ d2) {
  int bx = blockIdx.x;
  const float* s; short* d;
  if (bx < b0)           { s = s0; d = d0; }
  else if (bx < b0 + b1) { s = s1; d = d1; bx -= b0; }
  else                   { s = s2; d = d2; bx -= b0 + b1; }
  const int i = (bx * 256 + threadIdx.x) * 8;
  float4 a = *(const float4*)(s + i);
  float4 b = *(const float4*)(s + i + 4);
  union { frag16 f; short sh[8]; } u;
  u.sh[0] = f2bf(a.x); u.sh[1] = f2bf(a.y); u.sh[2] = f2bf(a.z); u.sh[3] = f2bf(a.w);
  u.sh[4] = f2bf(b.x); u.sh[5] = f2bf(b.y); u.sh[6] = f2bf(b.z); u.sh[7] = f2bf(b.w);
  *(frag16*)(d + i) = u.f;
}

// ---------------------------------------------------------------------------
// bf16 MFMA GEMM: C[M][Nc] = A[M][K] * W[Nc][K]^T.  M fixed = 4096 (32 tiles).
// 128x128 C-tile, 4 waves (2x2 of 64x64), BK=64 (32 barrier-pairs for K=2048),
// global_load_lds staging, XOR bank swizzle: phys 16B-chunk = logical ^ (row&7).
// ---------------------------------------------------------------------------
template <typename OutT>
__global__ __launch_bounds__(256) void gemm_mfma(const short* __restrict__ A,
                                                 const short* __restrict__ Wt,
                                                 OutT* __restrict__ C,
                                                 int Nc, int K, int ncpx) {
  __shared__ __align__(16) short As[128][64];  // 16 KB
  __shared__ __align__(16) short Bs[128][64];  // 16 KB

  const int bid = blockIdx.x;
  const int xcd = bid & 7, j = bid >> 3;
  const int m0 = (j & 31) * 128;
  const int n0 = (xcd * ncpx + (j >> 5)) * 128;

  const int tid = threadIdx.x;
  const int lane = tid & 63;
  const int w = tid >> 6;
  const int ln = lane & 15, g = lane >> 4;
  const int wm = (w >> 1) * 64, wn = (w & 1) * 64;

  // staging: lane l -> row (l>>3) within 8-row group, phys chunk l&7 holds
  // logical chunk (l&7) ^ (l>>3); 4 insts/lane/matrix cover 32 rows per wave
  const int srow = lane >> 3;                       // 0..7
  const int schunk = ((lane & 7) ^ srow) * 8;       // shorts offset in K
  // frag reads: phys chunk for (c,g) at row with row&7 == ln&7
  const int l7 = ln & 7;

  fragf4 acc[4][4];
#pragma unroll
  for (int i = 0; i < 4; ++i)
#pragma unroll
    for (int jj = 0; jj < 4; ++jj) acc[i][jj] = (fragf4){0.f, 0.f, 0.f, 0.f};

  for (int k0 = 0; k0 < K; k0 += 64) {
    __syncthreads();
#pragma unroll
    for (int i = 0; i < 4; ++i) {
      const int rbase = w * 32 + i * 8;
      const int r = rbase + srow;
      async_copy16(A  + (size_t)(m0 + r) * K + k0 + schunk, &As[rbase][0]);
      async_copy16(Wt + (size_t)(n0 + r) * K + k0 + schunk, &Bs[rbase][0]);
    }
    __syncthreads();

    frag16 af[2][4], bf[2][4];
#pragma unroll
    for (int c = 0; c < 2; ++c) {
      const int pc = (((c << 2) | g) ^ l7) * 8;
#pragma unroll
      for (int t = 0; t < 4; ++t) {
        af[c][t] = *(const frag16*)&As[wm + t * 16 + ln][pc];
        bf[c][t] = *(const frag16*)&Bs[wn + t * 16 + ln][pc];
      }
    }
#pragma unroll
    for (int c = 0; c < 2; ++c)
#pragma unroll
      for (int i = 0; i < 4; ++i)
#pragma unroll
        for (int jj = 0; jj < 4; ++jj)
          acc[i][jj] = MFMA16(af[c][i], bf[c][jj], acc[i][jj]);
  }

#pragma unroll
  for (int i = 0; i < 4; ++i) {
#pragma unroll
    for (int jj = 0; jj < 4; ++jj) {
#pragma unroll
      for (int r = 0; r < 4; ++r) {
        const size_t idx = (size_t)(m0 + wm + i * 16 + 4 * g + r) * Nc +
                           (n0 + wn + jj * 16 + ln);
        if constexpr (sizeof(OutT) == 2) C[idx] = f2bf(acc[i][jj][r]);
        else                             C[idx] = acc[i][jj][r];
      }
    }
  }
}

// ---------------------------------------------------------------------------
// Fused RMSNorm+RoPE (blocks [0, nrB)) + V-transpose (blocks [nrB, nrB+256))
// ---------------------------------------------------------------------------
__global__ __launch_bounds__(256) void normrope_vt(short* __restrict__ qkvb,
                                                   short* __restrict__ vtg,
                                                   const int* __restrict__ pos,
                                                   const float* __restrict__ qw,
                                                   const float* __restrict__ kw,
                                                   int nrB) {
  __shared__ short T[128 * 72];
  const int tid = threadIdx.x;

  if ((int)blockIdx.x < nrB) {
    const int gid = blockIdx.x * 256 + tid;
    const int lane = gid & 63;
    const int wid = gid >> 6;
    const int hh = wid % (HQ_ + HKV_);
    const int n  = (wid / (HQ_ + HKV_)) % N_;
    const int b  = wid / ((HQ_ + HKV_) * N_);

    int eoff; const float* w;
    if (hh < HQ_) { eoff = hh * DH_;              w = qw; }
    else          { eoff = D_ + (hh - HQ_) * DH_; w = kw; }

    short* base = qkvb + ((size_t)b * N_ + n) * E_ + eoff;
    union { uint32_t u; float f; } c1, c2;
    c1.u = ((uint32_t)(uint16_t)base[lane]) << 16;
    c2.u = ((uint32_t)(uint16_t)base[64 + lane]) << 16;
    float t1 = c1.f, t2 = c2.f;

    float ss = t1 * t1 + t2 * t2;
#pragma unroll
    for (int off = 32; off; off >>= 1) ss += __shfl_xor(ss, off);
    const float r = rsqrtf(ss * (1.0f / 128.0f) + 1.1920928955078125e-07f);
    t1 = t1 * r * w[lane];
    t2 = t2 * r * w[64 + lane];

    const float invf = (float)exp2(-(double)lane * 0.20762050593046014);
    const float ang = (float)pos[n] * invf;
    const float c = cosf(ang), s = sinf(ang);
    base[lane]      = f2bf(t1 * c - t2 * s);
    base[64 + lane] = f2bf(t2 * c + t1 * s);
  } else {
    const int idx = blockIdx.x - nrB;
    const int n0 = (idx & 15) * 64, kh = (idx >> 4) & 3, b = idx >> 6;
    {
      const int r = tid & 63, dc = (tid >> 6) * 32;
      const short* src = qkvb + ((size_t)b * N_ + n0 + r) * E_ + 2560 + kh * DH_ + dc;
      union { frag16 f; short s[8]; } u;
#pragma unroll
      for (int i = 0; i < 4; ++i) {
        u.f = *(const frag16*)(src + 8 * i);
#pragma unroll
        for (int jj = 0; jj < 8; ++jj) T[(dc + 8 * i + jj) * 72 + r] = u.s[jj];
      }
    }
    __syncthreads();
    {
      const int d = tid & 127, e = tid >> 7;
      short* dst = vtg + ((size_t)(b * HKV_ + kh) * DH_ + d) * N_ + n0 + e * 32;
#pragma unroll
      for (int i = 0; i < 4; ++i)
        *(frag16*)(dst + 8 * i) = *(const frag16*)&T[d * 72 + e * 32 + 8 * i];
    }
  }
}

// ---------------------------------------------------------------------------
// bf16-MFMA flash attention, fixed-max softmax (unchanged)
// ---------------------------------------------------------------------------
__global__ __launch_bounds__(256) void attn_mfma(const short* __restrict__ qkvb,
                                                 const short* __restrict__ vtg,
                                                 short* __restrict__ yb) {
  const int bx = blockIdx.x;
  const int qt = 63 - (bx >> 4);
  const int id = bx & 15;
  const int kh = id & 3, b = id >> 2;
  const int q0 = qt * 16;

  __shared__ __align__(16) short lds_[22600];
  const int VT0 = 8704, PS0 = 17992;

  const int tid = threadIdx.x;
  const int lane = tid & 63;
  const int w = tid >> 6;
  const int ln = lane & 15, g = lane >> 4, g8 = g * 8;
  const int h = kh * 4 + w;

  const short* qb = qkvb + (size_t)b * N_ * E_ + h * DH_;
  const short* kb = qkvb + (size_t)b * N_ * E_ + D_ + kh * DH_;
  const short* vt = vtg + (size_t)(b * HKV_ + kh) * DH_ * N_;

  if (tid < 64) lds_[VT0 + 128 * 72 + tid] = (short)0x3F80;

  frag16 qf[4];
  {
    const short* qrow = qb + (size_t)(q0 + ln) * E_ + g8;
#pragma unroll
    for (int c = 0; c < 4; ++c) qf[c] = *(const frag16*)(qrow + c * 32);
  }

  fragf4 o[8], ol = (fragf4){0.f, 0.f, 0.f, 0.f};
#pragma unroll
  for (int dt = 0; dt < 8; ++dt) o[dt] = (fragf4){0.f, 0.f, 0.f, 0.f};

  const float SC2 = (float)(SCALE_ * 1.4426950408889634);
  const float MB2 = (float)(12.0 * 1.4426950408889634);

  const int ntiles = qt / 4 + 1;
  for (int kt = 0; kt < ntiles; ++kt) {
    const int kbase = kt * 64;
    __syncthreads();
    {
      const int r = tid & 63, c = (tid >> 6) * 32;
      const short* src = kb + (size_t)(kbase + r) * E_ + c;
#pragma unroll
      for (int i = 0; i < 4; ++i)
        *(frag16*)&lds_[r * 136 + c + 8 * i] = *(const frag16*)(src + 8 * i);
    }
    {
      const int d = tid & 127, e = tid >> 7;
      const short* src = vt + (size_t)d * N_ + kbase + e * 32;
#pragma unroll
      for (int i = 0; i < 4; ++i)
        *(frag16*)&lds_[VT0 + d * 72 + e * 32 + 8 * i] = *(const frag16*)(src + 8 * i);
    }
    __syncthreads();

    fragf4 s[4];
#pragma unroll
    for (int st = 0; st < 4; ++st) s[st] = (fragf4){0.f, 0.f, 0.f, 0.f};
#pragma unroll
    for (int c = 0; c < 4; ++c) {
      frag16 qc = qf[c];
#pragma unroll
      for (int st = 0; st < 4; ++st) {
        frag16 kf = *(const frag16*)&lds_[(st * 16 + ln) * 136 + c * 32 + g8];
        s[st] = MFMA16(qc, kf, s[st]);
      }
    }

    const bool full = (kbase + 63) <= q0;
#pragma unroll
    for (int st = 0; st < 4; ++st) {
      const int kg = kbase + st * 16 + ln;
#pragma unroll
      for (int r2 = 0; r2 < 4; ++r2) {
        float sv = s[st][r2];
        if (!full && kg > q0 + 4 * g + r2) sv = -1.0e30f;
        const float p = exp2f(fmaf(sv, SC2, -MB2));
        lds_[PS0 + (w * 16 + 4 * g + r2) * 72 + st * 16 + ln] = f2bf_t(p);
      }
    }

    frag16 pf0 = *(const frag16*)&lds_[PS0 + (w * 16 + ln) * 72 + g8];
    frag16 pf1 = *(const frag16*)&lds_[PS0 + (w * 16 + ln) * 72 + 32 + g8];
#pragma unroll
    for (int dt = 0; dt < 8; ++dt) {
      frag16 v0 = *(const frag16*)&lds_[VT0 + (dt * 16 + ln) * 72 + g8];
      frag16 v1 = *(const frag16*)&lds_[VT0 + (dt * 16 + ln) * 72 + 32 + g8];
      o[dt] = MFMA16(pf0, v0, o[dt]);
      o[dt] = MFMA16(pf1, v1, o[dt]);
    }
    {
      frag16 vl0 = *(const frag16*)&lds_[VT0 + (128 + ln) * 72 + g8];
      frag16 vl1 = *(const frag16*)&lds_[VT0 + (128 + ln) * 72 + 32 + g8];
      ol = MFMA16(pf0, vl0, ol);
      ol = MFMA16(pf1, vl1, ol);
    }
  }

#pragma unroll
  for (int r2 = 0; r2 < 4; ++r2) {
    const float lv = __shfl(ol[r2], lane & 48);
    const float inv = 1.0f / lv;
    short* yrow = yb + ((size_t)b * N_ + q0 + 4 * g + r2) * D_ + h * DH_;
#pragma unroll
    for (int dt = 0; dt < 8; ++dt) yrow[dt * 16 + ln] = f2bf(o[dt][r2] * inv);
  }
}

// ---------------------------------------------------------------------------
extern "C" void kernel_launch(void* const* d_in, const int* in_sizes, int n_in,
                              void* d_out, int out_size, void* d_ws, size_t ws_size,
                              hipStream_t stream) {
  const float* x     = (const float*)d_in[0];
  const int*   pos   = (const int*)d_in[2];
  const float* w_qkv = (const float*)d_in[3];
  const float* w_out = (const float*)d_in[4];
  const float* qw    = (const float*)d_in[5];
  const float* kw    = (const float*)d_in[6];
  float* out = (float*)d_out;

  short* qkvb = (short*)d_ws;
  short* yb   = qkvb + (size_t)B_ * N_ * E_;
  short* xb   = yb   + (size_t)B_ * N_ * D_;
  short* wqb  = xb   + (size_t)B_ * N_ * D_;
  short* wob  = wqb  + (size_t)E_ * D_;
  short* vtg  = xb;  // alias, used post-gemm1

  const int nx = B_ * N_ * D_, nwq = E_ * D_, nwo = D_ * D_;
  const int bx_ = nx / 2048, bwq = nwq / 2048, bwo = nwo / 2048;
  f2bf3_kernel<<<bx_ + bwq + bwo, 256, 0, stream>>>(
      x, xb, bx_, w_qkv, wqb, bwq, w_out, wob);

  // GEMM1: M=4096, Nc=3072, K=2048 -> 768 blocks, ncpx = 3
  gemm_mfma<short><<<768, 256, 0, stream>>>(xb, wqb, qkvb, E_, D_, 3);

  const int nrB = (B_ * N_ * (HQ_ + HKV_) * 64) / 256;  // 20480
  normrope_vt<<<nrB + 256, 256, 0, stream>>>(qkvb, vtg, pos, qw, kw, nrB);

  attn_mfma<<<1024, 256, 0, stream>>>(qkvb, vtg, yb);

  // GEMM2: M=4096, Nc=2048, K=2048 -> 512 blocks, ncpx = 2
  gemm_mfma<float><<<512, 256, 0, stream>>>(yb, wob, out, D_, D_, 2);
}